// Round 6
// baseline (215.611 us; speedup 1.0000x reference)
//
#include <hip/hip_runtime.h>
#include <hip/hip_fp16.h>

#define NN 50000
#define NE 800000
#define DD 64
#define NG 64

#define NBKT 196        // ceil(NN/256) coarse buckets (dst >> 8)
#define MAXB 5120       // padded tmp slots per bucket (mean 4082)
#define P1CH 4096       // edges per pass-1 block
#define P1NB ((NE + P1CH - 1) / P1CH)   // 196

// ---------------- init: bucket bases + pool accumulators ----------------
__global__ void init_k(int* __restrict__ bucket_pos,
                       float* __restrict__ sums, float* __restrict__ cnts) {
    int i = blockIdx.x * blockDim.x + threadIdx.x;
    if (i < NBKT) bucket_pos[i] = i * MAXB;
    if (i < NG * DD) sums[i] = 0.0f;
    if (i < NG) cnts[i] = 0.0f;
}

// ---------------- pass 1: bin edges by dst>>8 into padded tmp buckets ----------------
__global__ __launch_bounds__(256) void bin_k(const int* __restrict__ ei,
                                             const float* __restrict__ ew,
                                             int* __restrict__ bucket_pos,
                                             unsigned int* __restrict__ tmp_pay,
                                             unsigned char* __restrict__ tmp_c8) {
    __shared__ int hist[NBKT];
    __shared__ int basec[NBKT];
    const int t = threadIdx.x;
    const int e0 = blockIdx.x * P1CH;
    for (int i = t; i < NBKT; i += 256) hist[i] = 0;
    __syncthreads();
    int rr[16]; int cc[16]; float wwf[16];
    #pragma unroll
    for (int i = 0; i < 16; ++i) {
        int e = e0 + i * 256 + t;
        if (e < NE) {
            rr[i] = ei[e]; cc[i] = ei[NE + e]; wwf[i] = ew[e];
            atomicAdd(&hist[cc[i] >> 8], 1);
        } else cc[i] = -1;
    }
    __syncthreads();
    // one global atomic per (block, bucket): reserve contiguous region
    for (int i = t; i < NBKT; i += 256) basec[i] = atomicAdd(&bucket_pos[i], hist[i]);
    __syncthreads();
    #pragma unroll
    for (int i = 0; i < 16; ++i) {
        if (cc[i] >= 0) {
            int b = cc[i] >> 8;
            int slot = atomicAdd(&basec[b], 1);   // LDS cursor within reservation
            unsigned int hb = (unsigned int)__half_as_ushort(__float2half(wwf[i]));
            tmp_pay[slot] = (hb << 16) | (unsigned int)rr[i];
            tmp_c8[slot] = (unsigned char)(cc[i] & 255);
        }
    }
}

// ---------------- scan of bucket counts -> global bucket bases ----------------
__global__ __launch_bounds__(256) void bscan_k(const int* __restrict__ bucket_pos,
                                               int* __restrict__ gbase,
                                               int* __restrict__ rowptr) {
    __shared__ int wtot[4];
    const int t = threadIdx.x;
    int v = (t < NBKT) ? (bucket_pos[t] - t * MAXB) : 0;
    int pre = v;
    #pragma unroll
    for (int off = 1; off < 64; off <<= 1) {
        int u = __shfl_up(pre, off);
        if ((t & 63) >= off) pre += u;
    }
    if ((t & 63) == 63) wtot[t >> 6] = pre;
    __syncthreads();
    int woff = 0;
    for (int i = 0; i < (t >> 6); ++i) woff += wtot[i];
    if (t < NBKT) gbase[t] = woff + pre - v;
    if (t == 0) rowptr[NN] = NE;
}

// ---------------- pass 2: per-bucket exact sort + rowptr + dis ----------------
__global__ __launch_bounds__(256) void build_k(const int* __restrict__ bucket_pos,
                                               const int* __restrict__ gbase,
                                               const unsigned int* __restrict__ tmp_pay,
                                               const unsigned char* __restrict__ tmp_c8,
                                               unsigned int* __restrict__ srt,
                                               int* __restrict__ rowptr,
                                               float* __restrict__ dis) {
    __shared__ int hist[256];
    __shared__ int cursor[256];
    __shared__ float degf[256];
    __shared__ int wtot[4];
    const int b = blockIdx.x;
    const int t = threadIdx.x;
    const int cntb = bucket_pos[b] - b * MAXB;
    const int tbase = b * MAXB;
    hist[t] = 0; degf[t] = 0.0f;
    __syncthreads();
    for (int i = t; i < cntb; i += 256) atomicAdd(&hist[tmp_c8[tbase + i]], 1);
    __syncthreads();
    // exclusive scan of hist (256 values, 4 waves)
    int v = hist[t];
    int pre = v;
    #pragma unroll
    for (int off = 1; off < 64; off <<= 1) {
        int u = __shfl_up(pre, off);
        if ((t & 63) >= off) pre += u;
    }
    if ((t & 63) == 63) wtot[t >> 6] = pre;
    __syncthreads();
    int woff = 0;
    for (int i = 0; i < (t >> 6); ++i) woff += wtot[i];
    const int excl = gbase[b] + woff + pre - v;
    const int node = b * 256 + t;
    if (node < NN) rowptr[node] = excl;
    cursor[t] = excl;
    __syncthreads();
    for (int i = t; i < cntb; i += 256) {
        unsigned int u = tmp_pay[tbase + i];
        int c8 = tmp_c8[tbase + i];
        int slot = atomicAdd(&cursor[c8], 1);   // LDS
        srt[slot] = u;
        float w = __half2float(__ushort_as_half((unsigned short)(u >> 16)));
        atomicAdd(&degf[c8], w);                // LDS fp32
    }
    __syncthreads();
    if (node < NN) dis[node] = rsqrtf(1.0f + degf[t]);
}

// ---------------- GEMM: A' = (act(X) @ W) * dis[row], fp16 out ----------------
// 64 rows/block, 4x4 register tile per thread, b128 LDS reads.
template<bool ACT>
__global__ __launch_bounds__(256) void gemm_k(
    const float* __restrict__ X, const float* __restrict__ W,
    const float* __restrict__ bias_prev, const float* __restrict__ dis,
    __half* __restrict__ Ah)
{
    __shared__ float Ws[64][64];
    __shared__ float Xt[64][68];   // transposed, padded to keep float4 alignment
    const int t = threadIdx.x;
    const int row0 = blockIdx.x * 64;

    #pragma unroll
    for (int s = t; s < 64 * 64; s += 256) Ws[s >> 6][s & 63] = W[s];
    #pragma unroll
    for (int s = t; s < 64 * 64; s += 256) {
        int r = s >> 6, k = s & 63;
        int row = row0 + r;
        if (row >= NN) row = NN - 1;   // clamp (last block tail)
        float v = X[(size_t)row * DD + k];
        if (ACT) v = fmaxf(v + bias_prev[k], 0.0f);
        Xt[k][r] = v;
    }
    __syncthreads();

    const int tc = t & 15;   // col group: cols tc*4..tc*4+3
    const int tr = t >> 4;   // row group: rows tr*4..tr*4+3
    float acc[4][4];
    #pragma unroll
    for (int i = 0; i < 4; ++i)
        #pragma unroll
        for (int j = 0; j < 4; ++j) acc[i][j] = 0.0f;

    const float4* xp = (const float4*)&Xt[0][tr * 4];  // stride 17 float4 per k
    const float4* wp = (const float4*)&Ws[0][tc * 4];  // stride 16 float4 per k
    #pragma unroll
    for (int k = 0; k < 64; ++k) {
        float4 xv = xp[k * 17];
        float4 wv = wp[k * 16];
        acc[0][0] += xv.x * wv.x; acc[0][1] += xv.x * wv.y; acc[0][2] += xv.x * wv.z; acc[0][3] += xv.x * wv.w;
        acc[1][0] += xv.y * wv.x; acc[1][1] += xv.y * wv.y; acc[1][2] += xv.y * wv.z; acc[1][3] += xv.y * wv.w;
        acc[2][0] += xv.z * wv.x; acc[2][1] += xv.z * wv.y; acc[2][2] += xv.z * wv.z; acc[2][3] += xv.z * wv.w;
        acc[3][0] += xv.w * wv.x; acc[3][1] += xv.w * wv.y; acc[3][2] += xv.w * wv.z; acc[3][3] += xv.w * wv.w;
    }

    #pragma unroll
    for (int i = 0; i < 4; ++i) {
        int row = row0 + tr * 4 + i;
        if (row >= NN) break;
        float d = dis[row];
        __half2 h0 = __floats2half2_rn(acc[i][0] * d, acc[i][1] * d);
        __half2 h1 = __floats2half2_rn(acc[i][2] * d, acc[i][3] * d);
        uint2 st;
        st.x = *reinterpret_cast<unsigned int*>(&h0);
        st.y = *reinterpret_cast<unsigned int*>(&h1);
        *reinterpret_cast<uint2*>(&Ah[(size_t)row * DD + tc * 4]) = st;
    }
}

// ---------------- gather: B[c] = dis[c] * (A'[c] + sum_e w_e * A'[r_e]) ----------------
// 2 edges per wave-iteration: lanes 0-31 = edge e, lanes 32-63 = edge e+1,
// each lane loads __half2 (2 features).
__global__ __launch_bounds__(256) void gather_k(
    const int* __restrict__ rowptr, const unsigned int* __restrict__ srt,
    const float* __restrict__ dis,
    const __half2* __restrict__ Ah2, float* __restrict__ B)
{
    const int wl = threadIdx.x & 63;
    const int node = blockIdx.x * 4 + (threadIdx.x >> 6);
    const int h = wl >> 5;     // which edge of the pair
    const int l = wl & 31;     // feature pair index
    if (node >= NN) return;

    float2 acc = make_float2(0.0f, 0.0f);
    if (h == 0) {              // self-loop term on lower half
        __half2 s = Ah2[(size_t)node * 32 + l];
        acc.x = __half2float(__low2half(s));
        acc.y = __half2float(__high2half(s));
    }
    int e = rowptr[node];
    const int end = rowptr[node + 1];
    for (; e + 3 < end; e += 4) {
        unsigned int u0 = srt[e + h];
        unsigned int u1 = srt[e + 2 + h];
        __half2 a0 = Ah2[(size_t)(u0 & 0xffffu) * 32 + l];
        __half2 a1 = Ah2[(size_t)(u1 & 0xffffu) * 32 + l];
        float w0 = __half2float(__ushort_as_half((unsigned short)(u0 >> 16)));
        float w1 = __half2float(__ushort_as_half((unsigned short)(u1 >> 16)));
        acc.x += w0 * __half2float(__low2half(a0));
        acc.y += w0 * __half2float(__high2half(a0));
        acc.x += w1 * __half2float(__low2half(a1));
        acc.y += w1 * __half2float(__high2half(a1));
    }
    for (; e < end; e += 2) {
        int idx = e + h;
        if (idx < end) {
            unsigned int u0 = srt[idx];
            __half2 a0 = Ah2[(size_t)(u0 & 0xffffu) * 32 + l];
            float w0 = __half2float(__ushort_as_half((unsigned short)(u0 >> 16)));
            acc.x += w0 * __half2float(__low2half(a0));
            acc.y += w0 * __half2float(__high2half(a0));
        }
    }
    // combine the two half-wave partials
    acc.x += __shfl_xor(acc.x, 32);
    acc.y += __shfl_xor(acc.y, 32);
    if (h == 0) {
        float d = dis[node];
        *reinterpret_cast<float2*>(&B[(size_t)node * DD + l * 2]) =
            make_float2(d * acc.x, d * acc.y);
    }
}

// ---------------- pooling ----------------
__global__ __launch_bounds__(64) void pool(
    const float* __restrict__ B, const float* __restrict__ b2,
    const int* __restrict__ batch,
    float* __restrict__ sums, float* __restrict__ cnts, int n)
{
    const int lane = threadIdx.x;
    const int start = blockIdx.x * 128;
    const int end = min(start + 128, n);
    const float bb = b2[lane];
    float acc = 0.0f;
    int cn = 0;
    int curg = batch[start];
    for (int i = start; i < end; ++i) {
        int g = batch[i];
        if (g != curg) {
            unsafeAtomicAdd(&sums[curg * DD + lane], acc);
            if (lane == 0) unsafeAtomicAdd(&cnts[curg], (float)cn);
            acc = 0.0f; cn = 0; curg = g;
        }
        acc += fmaxf(B[(size_t)i * DD + lane] + bb, 0.0f);
        cn++;
    }
    if (cn > 0) {
        unsafeAtomicAdd(&sums[curg * DD + lane], acc);
        if (lane == 0) unsafeAtomicAdd(&cnts[curg], (float)cn);
    }
}

__global__ void finalize(const float* __restrict__ sums, const float* __restrict__ cnts,
                         float* __restrict__ out) {
    int i = blockIdx.x * blockDim.x + threadIdx.x;
    if (i < NG * DD) {
        int g = i >> 6;
        out[i] = sums[i] / fmaxf(cnts[g], 1.0f);
    }
}

// ---------------- host ----------------
extern "C" void kernel_launch(void* const* d_in, const int* in_sizes, int n_in,
                              void* d_out, int out_size, void* d_ws, size_t ws_size,
                              hipStream_t stream) {
    const float* x   = (const float*)d_in[0];
    const int*   ei  = (const int*)  d_in[1];
    const float* ew  = (const float*)d_in[2];
    const int*   bat = (const int*)  d_in[3];
    const float* W1  = (const float*)d_in[4];
    const float* b1  = (const float*)d_in[5];
    const float* W2  = (const float*)d_in[6];
    const float* b2  = (const float*)d_in[7];
    float* out = (float*)d_out;

    char* ws = (char*)d_ws;
    size_t off = 0;
    __half* Ah        = (__half*)(ws + off); off += (size_t)NN * DD * 2;          // 6.4 MB
    float*  B         = (float*) (ws + off); off += (size_t)NN * DD * 4;          // 12.8 MB
    unsigned int* srt = (unsigned int*)(ws + off); off += (size_t)NE * 4;         // 3.2 MB
    unsigned int* tmp_pay = (unsigned int*)(ws + off); off += (size_t)NBKT * MAXB * 4;  // 4.0 MB
    unsigned char* tmp_c8 = (unsigned char*)(ws + off); off += (size_t)NBKT * MAXB;     // 1.0 MB
    int*    bucket_pos = (int*)(ws + off); off += (size_t)NBKT * 4;
    int*    gbase      = (int*)(ws + off); off += (size_t)NBKT * 4;
    int*    rowptr     = (int*)(ws + off); off += (size_t)(NN + 1) * 4;
    float*  dis        = (float*)(ws + off); off += (size_t)NN * 4;
    float*  sums       = (float*)(ws + off); off += (size_t)NG * DD * 4;
    float*  cnts       = (float*)(ws + off); off += (size_t)NG * 4;

    // CSR + normalization build (shared by both layers) — no per-edge global atomics
    init_k<<<(NG * DD + 255) / 256, 256, 0, stream>>>(bucket_pos, sums, cnts);
    bin_k<<<P1NB, 256, 0, stream>>>(ei, ew, bucket_pos, tmp_pay, tmp_c8);
    bscan_k<<<1, 256, 0, stream>>>(bucket_pos, gbase, rowptr);
    build_k<<<NBKT, 256, 0, stream>>>(bucket_pos, gbase, tmp_pay, tmp_c8, srt, rowptr, dis);

    // layer 1
    gemm_k<false><<<(NN + 63) / 64, 256, 0, stream>>>(x, W1, nullptr, dis, Ah);
    gather_k<<<(NN + 3) / 4, 256, 0, stream>>>(rowptr, srt, dis, (const __half2*)Ah, B);

    // layer 2
    gemm_k<true><<<(NN + 63) / 64, 256, 0, stream>>>(B, W2, b1, dis, Ah);
    gather_k<<<(NN + 3) / 4, 256, 0, stream>>>(rowptr, srt, dis, (const __half2*)Ah, B);

    // pooling (bias+relu fused on read)
    pool<<<(NN + 127) / 128, 64, 0, stream>>>(B, b2, bat, sums, cnts, NN);
    finalize<<<(NG * DD + 255) / 256, 256, 0, stream>>>(sums, cnts, out);
}

// Round 7
// 177.279 us; speedup vs baseline: 1.2162x; 1.2162x over previous
//
#include <hip/hip_runtime.h>
#include <hip/hip_fp16.h>

#define NN 50000
#define NE 800000
#define DD 64
#define NG 64

#define NBKT 196        // ceil(NN/256) coarse buckets (dst >> 8)
#define MAXB 5120       // padded tmp slots per bucket (mean 4082)
#define SRTB 7168       // srt slots per bucket (>= MAXB + 256*7 pad worst case)
#define P1CH 4096       // edges per pass-1 block
#define P1NB ((NE + P1CH - 1) / P1CH)   // 196

// ---------------- init: bucket bases + pool accumulators ----------------
__global__ void init_k(int* __restrict__ bucket_pos,
                       float* __restrict__ sums, float* __restrict__ cnts) {
    int i = blockIdx.x * blockDim.x + threadIdx.x;
    if (i < NBKT) bucket_pos[i] = i * MAXB;
    if (i < NG * DD) sums[i] = 0.0f;
    if (i < NG) cnts[i] = 0.0f;
}

// ---------------- pass 1: bin edges by dst>>8 into padded tmp buckets ----------------
__global__ __launch_bounds__(256) void bin_k(const int* __restrict__ ei,
                                             const float* __restrict__ ew,
                                             int* __restrict__ bucket_pos,
                                             unsigned int* __restrict__ tmp_pay,
                                             unsigned char* __restrict__ tmp_c8) {
    __shared__ int hist[NBKT];
    __shared__ int basec[NBKT];
    const int t = threadIdx.x;
    const int e0 = blockIdx.x * P1CH;
    for (int i = t; i < NBKT; i += 256) hist[i] = 0;
    __syncthreads();
    int rr[16]; int cc[16]; float wwf[16];
    #pragma unroll
    for (int i = 0; i < 16; ++i) {
        int e = e0 + i * 256 + t;
        if (e < NE) {
            rr[i] = ei[e]; cc[i] = ei[NE + e]; wwf[i] = ew[e];
            atomicAdd(&hist[cc[i] >> 8], 1);
        } else cc[i] = -1;
    }
    __syncthreads();
    // one global atomic per (block, bucket): reserve contiguous region
    for (int i = t; i < NBKT; i += 256) basec[i] = atomicAdd(&bucket_pos[i], hist[i]);
    __syncthreads();
    #pragma unroll
    for (int i = 0; i < 16; ++i) {
        if (cc[i] >= 0) {
            int b = cc[i] >> 8;
            int slot = atomicAdd(&basec[b], 1);   // LDS cursor within reservation
            unsigned int hb = (unsigned int)__half_as_ushort(__float2half(wwf[i]));
            tmp_pay[slot] = (hb << 16) | (unsigned int)rr[i];
            tmp_c8[slot] = (unsigned char)(cc[i] & 255);
        }
    }
}

// ---------------- pass 2: per-bucket exact sort + per-node (start,pcnt) + dis ----------
// Segments padded to multiple of 8 with (r=0,w=0) dummy edges; each bucket owns a
// fixed srt window [b*SRTB, (b+1)*SRTB) so no global scan is needed.
__global__ __launch_bounds__(256) void build_k(const int* __restrict__ bucket_pos,
                                               const unsigned int* __restrict__ tmp_pay,
                                               const unsigned char* __restrict__ tmp_c8,
                                               unsigned int* __restrict__ srt,
                                               int2* __restrict__ rowse,
                                               float* __restrict__ dis) {
    __shared__ int hist[256];
    __shared__ int cursor[256];
    __shared__ float degf[256];
    __shared__ int wtot[4];
    const int b = blockIdx.x;
    const int t = threadIdx.x;
    const int cntb = bucket_pos[b] - b * MAXB;
    const int tbase = b * MAXB;
    hist[t] = 0; degf[t] = 0.0f;
    __syncthreads();
    for (int i = t; i < cntb; i += 256) atomicAdd(&hist[tmp_c8[tbase + i]], 1);
    __syncthreads();
    // exclusive scan of PADDED counts (256 values, 4 waves)
    const int v = hist[t];
    const int pv = (v + 7) & ~7;
    int pre = pv;
    #pragma unroll
    for (int off = 1; off < 64; off <<= 1) {
        int u = __shfl_up(pre, off);
        if ((t & 63) >= off) pre += u;
    }
    if ((t & 63) == 63) wtot[t >> 6] = pre;
    __syncthreads();
    int woff = 0;
    for (int i = 0; i < (t >> 6); ++i) woff += wtot[i];
    const int start = b * SRTB + woff + pre - pv;
    cursor[t] = start;
    __syncthreads();
    for (int i = t; i < cntb; i += 256) {
        unsigned int u = tmp_pay[tbase + i];
        int c8 = tmp_c8[tbase + i];
        int slot = atomicAdd(&cursor[c8], 1);   // LDS
        srt[slot] = u;
        float w = __half2float(__ushort_as_half((unsigned short)(u >> 16)));
        atomicAdd(&degf[c8], w);                // LDS fp32
    }
    __syncthreads();
    // fill this node's pad slots with zero-weight dummies
    for (int i = start + v; i < start + pv; ++i) srt[i] = 0u;
    const int node = b * 256 + t;
    if (node < NN) {
        rowse[node] = make_int2(start, pv);
        dis[node] = rsqrtf(1.0f + degf[t]);
    }
}

// ---------------- GEMM: A' = (act(X) @ W) * dis[row], fp16 out ----------------
// 64 rows/block, 4x4 register tile per thread, b128 LDS reads.
template<bool ACT>
__global__ __launch_bounds__(256) void gemm_k(
    const float* __restrict__ X, const float* __restrict__ W,
    const float* __restrict__ bias_prev, const float* __restrict__ dis,
    __half* __restrict__ Ah)
{
    __shared__ float Ws[64][64];
    __shared__ float Xt[64][68];   // transposed, padded to keep float4 alignment
    const int t = threadIdx.x;
    const int row0 = blockIdx.x * 64;

    #pragma unroll
    for (int s = t; s < 64 * 64; s += 256) Ws[s >> 6][s & 63] = W[s];
    #pragma unroll
    for (int s = t; s < 64 * 64; s += 256) {
        int r = s >> 6, k = s & 63;
        int row = row0 + r;
        if (row >= NN) row = NN - 1;   // clamp (last block tail)
        float v = X[(size_t)row * DD + k];
        if (ACT) v = fmaxf(v + bias_prev[k], 0.0f);
        Xt[k][r] = v;
    }
    __syncthreads();

    const int tc = t & 15;   // col group: cols tc*4..tc*4+3
    const int tr = t >> 4;   // row group: rows tr*4..tr*4+3
    float acc[4][4];
    #pragma unroll
    for (int i = 0; i < 4; ++i)
        #pragma unroll
        for (int j = 0; j < 4; ++j) acc[i][j] = 0.0f;

    const float4* xp = (const float4*)&Xt[0][tr * 4];  // stride 17 float4 per k
    const float4* wp = (const float4*)&Ws[0][tc * 4];  // stride 16 float4 per k
    #pragma unroll
    for (int k = 0; k < 64; ++k) {
        float4 xv = xp[k * 17];
        float4 wv = wp[k * 16];
        acc[0][0] += xv.x * wv.x; acc[0][1] += xv.x * wv.y; acc[0][2] += xv.x * wv.z; acc[0][3] += xv.x * wv.w;
        acc[1][0] += xv.y * wv.x; acc[1][1] += xv.y * wv.y; acc[1][2] += xv.y * wv.z; acc[1][3] += xv.y * wv.w;
        acc[2][0] += xv.z * wv.x; acc[2][1] += xv.z * wv.y; acc[2][2] += xv.z * wv.z; acc[2][3] += xv.z * wv.w;
        acc[3][0] += xv.w * wv.x; acc[3][1] += xv.w * wv.y; acc[3][2] += xv.w * wv.z; acc[3][3] += xv.w * wv.w;
    }

    #pragma unroll
    for (int i = 0; i < 4; ++i) {
        int row = row0 + tr * 4 + i;
        if (row >= NN) break;
        float d = dis[row];
        __half2 h0 = __floats2half2_rn(acc[i][0] * d, acc[i][1] * d);
        __half2 h1 = __floats2half2_rn(acc[i][2] * d, acc[i][3] * d);
        uint2 st;
        st.x = *reinterpret_cast<unsigned int*>(&h0);
        st.y = *reinterpret_cast<unsigned int*>(&h1);
        *reinterpret_cast<uint2*>(&Ah[(size_t)row * DD + tc * 4]) = st;
    }
}

// ---------------- gather: B[c] = dis[c] * (A'[c] + sum_e w_e * A'[r_e]) ----------------
// One wave per node, full 64-lane row loads, 8 independent rows in flight per iter.
__global__ __launch_bounds__(256) void gather_k(
    const int2* __restrict__ rowse, const unsigned int* __restrict__ srt,
    const float* __restrict__ dis,
    const __half* __restrict__ Ah, float* __restrict__ B)
{
    const int node = blockIdx.x * 4 + (threadIdx.x >> 6);
    const int lane = threadIdx.x & 63;
    if (node >= NN) return;
    const int2 se = rowse[node];
    float acc0 = __half2float(Ah[(size_t)node * DD + lane]);  // self-loop term
    float acc1 = 0.0f, acc2 = 0.0f, acc3 = 0.0f;
    const unsigned int* p = srt + se.x;
    for (int n = se.y; n > 0; n -= 8, p += 8) {
        uint4 u0 = *reinterpret_cast<const uint4*>(p);
        uint4 u1 = *reinterpret_cast<const uint4*>(p + 4);
        __half h0 = Ah[(size_t)(u0.x & 0xffffu) * DD + lane];
        __half h1 = Ah[(size_t)(u0.y & 0xffffu) * DD + lane];
        __half h2 = Ah[(size_t)(u0.z & 0xffffu) * DD + lane];
        __half h3 = Ah[(size_t)(u0.w & 0xffffu) * DD + lane];
        __half h4 = Ah[(size_t)(u1.x & 0xffffu) * DD + lane];
        __half h5 = Ah[(size_t)(u1.y & 0xffffu) * DD + lane];
        __half h6 = Ah[(size_t)(u1.z & 0xffffu) * DD + lane];
        __half h7 = Ah[(size_t)(u1.w & 0xffffu) * DD + lane];
        acc0 += __half2float(__ushort_as_half((unsigned short)(u0.x >> 16))) * __half2float(h0);
        acc1 += __half2float(__ushort_as_half((unsigned short)(u0.y >> 16))) * __half2float(h1);
        acc2 += __half2float(__ushort_as_half((unsigned short)(u0.z >> 16))) * __half2float(h2);
        acc3 += __half2float(__ushort_as_half((unsigned short)(u0.w >> 16))) * __half2float(h3);
        acc0 += __half2float(__ushort_as_half((unsigned short)(u1.x >> 16))) * __half2float(h4);
        acc1 += __half2float(__ushort_as_half((unsigned short)(u1.y >> 16))) * __half2float(h5);
        acc2 += __half2float(__ushort_as_half((unsigned short)(u1.z >> 16))) * __half2float(h6);
        acc3 += __half2float(__ushort_as_half((unsigned short)(u1.w >> 16))) * __half2float(h7);
    }
    B[(size_t)node * DD + lane] = dis[node] * ((acc0 + acc1) + (acc2 + acc3));
}

// ---------------- pooling: 32 rows per block ----------------
__global__ __launch_bounds__(64) void pool(
    const float* __restrict__ B, const float* __restrict__ b2,
    const int* __restrict__ batch,
    float* __restrict__ sums, float* __restrict__ cnts, int n)
{
    const int lane = threadIdx.x;
    const int start = blockIdx.x * 32;
    const int end = min(start + 32, n);
    const float bb = b2[lane];
    float acc = 0.0f;
    int cn = 0;
    int curg = batch[start];
    for (int i = start; i < end; ++i) {
        int g = batch[i];
        if (g != curg) {
            unsafeAtomicAdd(&sums[curg * DD + lane], acc);
            if (lane == 0) unsafeAtomicAdd(&cnts[curg], (float)cn);
            acc = 0.0f; cn = 0; curg = g;
        }
        acc += fmaxf(B[(size_t)i * DD + lane] + bb, 0.0f);
        cn++;
    }
    if (cn > 0) {
        unsafeAtomicAdd(&sums[curg * DD + lane], acc);
        if (lane == 0) unsafeAtomicAdd(&cnts[curg], (float)cn);
    }
}

__global__ void finalize(const float* __restrict__ sums, const float* __restrict__ cnts,
                         float* __restrict__ out) {
    int i = blockIdx.x * blockDim.x + threadIdx.x;
    if (i < NG * DD) {
        int g = i >> 6;
        out[i] = sums[i] / fmaxf(cnts[g], 1.0f);
    }
}

// ---------------- host ----------------
extern "C" void kernel_launch(void* const* d_in, const int* in_sizes, int n_in,
                              void* d_out, int out_size, void* d_ws, size_t ws_size,
                              hipStream_t stream) {
    const float* x   = (const float*)d_in[0];
    const int*   ei  = (const int*)  d_in[1];
    const float* ew  = (const float*)d_in[2];
    const int*   bat = (const int*)  d_in[3];
    const float* W1  = (const float*)d_in[4];
    const float* b1  = (const float*)d_in[5];
    const float* W2  = (const float*)d_in[6];
    const float* b2  = (const float*)d_in[7];
    float* out = (float*)d_out;

    char* ws = (char*)d_ws;
    size_t off = 0;
    __half* Ah        = (__half*)(ws + off); off += (size_t)NN * DD * 2;          // 6.4 MB
    float*  B         = (float*) (ws + off); off += (size_t)NN * DD * 4;          // 12.8 MB
    unsigned int* srt = (unsigned int*)(ws + off); off += (size_t)NBKT * SRTB * 4; // 5.6 MB
    unsigned int* tmp_pay = (unsigned int*)(ws + off); off += (size_t)NBKT * MAXB * 4;  // 4.0 MB
    unsigned char* tmp_c8 = (unsigned char*)(ws + off); off += (size_t)NBKT * MAXB;     // 1.0 MB
    int*    bucket_pos = (int*)(ws + off); off += (size_t)NBKT * 4;
    int2*   rowse      = (int2*)(ws + off); off += (size_t)NN * 8;
    float*  dis        = (float*)(ws + off); off += (size_t)NN * 4;
    float*  sums       = (float*)(ws + off); off += (size_t)NG * DD * 4;
    float*  cnts       = (float*)(ws + off); off += (size_t)NG * 4;

    // CSR + normalization build (shared by both layers) — no per-edge global atomics
    init_k<<<(NG * DD + 255) / 256, 256, 0, stream>>>(bucket_pos, sums, cnts);
    bin_k<<<P1NB, 256, 0, stream>>>(ei, ew, bucket_pos, tmp_pay, tmp_c8);
    build_k<<<NBKT, 256, 0, stream>>>(bucket_pos, tmp_pay, tmp_c8, srt, rowse, dis);

    // layer 1
    gemm_k<false><<<(NN + 63) / 64, 256, 0, stream>>>(x, W1, nullptr, dis, Ah);
    gather_k<<<(NN + 3) / 4, 256, 0, stream>>>(rowse, srt, dis, Ah, B);

    // layer 2
    gemm_k<true><<<(NN + 63) / 64, 256, 0, stream>>>(B, W2, b1, dis, Ah);
    gather_k<<<(NN + 3) / 4, 256, 0, stream>>>(rowse, srt, dis, Ah, B);

    // pooling (bias+relu fused on read)
    pool<<<(NN + 31) / 32, 64, 0, stream>>>(B, b2, bat, sums, cnts, NN);
    finalize<<<(NG * DD + 255) / 256, 256, 0, stream>>>(sums, cnts, out);
}